// Round 6
// baseline (229.534 us; speedup 1.0000x reference)
//
#include <hip/hip_runtime.h>
#include <math.h>

#define B_ 32
#define C_ 256
#define HW_ 3136      // 56*56
#define HW4_ 784      // HW/4 (float4 chunks); 784 = 3*256 + 16
#define G_ 32
#define EPS_ 1e-5f

#define GRID_ 1024    // 4 blocks/CU * 256 CU = exact guaranteed co-residency
#define PPB_ 8        // planes per block; block bid -> planes [bid*8, bid*8+8), one image

typedef float v4f __attribute__((ext_vector_type(4)));

// ws layout: per image img, one 128B line: ws32[img*32 + 0] = z (float),
//                                          ws32[img*32 + 1] = cnt (uint)
// memset to 0 per launch (4 KB).

__global__ __launch_bounds__(256, 4) void fused_kernel(
    const float* __restrict__ x,
    const float* __restrict__ alpha_w, const float* __restrict__ alpha_b,
    const float* __restrict__ g_w, const float* __restrict__ g_b,
    const float* __restrict__ g_rm, const float* __restrict__ g_rv,
    const float* __restrict__ grp_w, const float* __restrict__ grp_b,
    const float* __restrict__ grp_rm, const float* __restrict__ grp_rv,
    float* __restrict__ ws, float* __restrict__ out)
{
    const int bid = blockIdx.x, tid = threadIdx.x;
    const int lane = tid & 63, wv = tid >> 6;
    const int p0 = bid * PPB_;
    const int img = bid >> 5;
    const int c0 = p0 & (C_ - 1);
    const v4f* __restrict__ xb = (const v4f*)(x + (size_t)p0 * HW_);
    v4f* __restrict__ ob = (v4f*)(out + (size_t)p0 * HW_);

    float* z_p = ws + (size_t)img * 32;                 // float accumulator
    unsigned int* cnt_p = (unsigned int*)(z_p + 1);     // arrival counter (same line)

    __shared__ float red[4][PPB_];
    __shared__ float gs_sh[PPB_], gsh_sh[PPB_], dsc_sh[PPB_], dsh_sh[PPB_];
    __shared__ float a_sh;

    v4f  v0[PPB_], v1[PPB_];   // 64 regs of plane data, pinned across the barrier
    float s[PPB_];

    // ---- phase 1: load, pool 8 planes; pin chunks 0,1 in registers ----
    #pragma unroll
    for (int t = 0; t < PPB_; ++t) {
        const int base = t * HW4_;
        v0[t] = xb[base + tid];
        v1[t] = xb[base + 256 + tid];
        v4f v2 = xb[base + 512 + tid];          // transient: summed now, re-read (L3) later
        float st = v0[t].x + v0[t].y + v0[t].z + v0[t].w;
        st += v1[t].x + v1[t].y + v1[t].z + v1[t].w;
        st += v2.x + v2.y + v2.z + v2.w;
        if (tid < 16) {                          // tail (2%): re-read from L2/L3 later
            v4f w = xb[base + 768 + tid];
            st += w.x + w.y + w.z + w.w;
        }
        s[t] = st;
        // forbid rematerialization: compiler must hold v0/v1 from here on
        asm volatile("" : "+v"(v0[t]), "+v"(v1[t]));
    }
    #pragma unroll
    for (int t = 0; t < PPB_; ++t) {
        float st = s[t];
        #pragma unroll
        for (int off = 32; off; off >>= 1) st += __shfl_down(st, off);
        if (lane == 0) red[wv][t] = st;
    }
    __syncthreads();

    // ---- arrival: one relaxed float-add + one release increment per block ----
    if (tid == 0) {
        float partial = 0.f;
        #pragma unroll
        for (int t = 0; t < PPB_; ++t) {
            float pooled_t = (red[0][t] + red[1][t] + red[2][t] + red[3][t])
                             * (1.f / HW_);
            partial += pooled_t * alpha_w[c0 + t];
        }
        __hip_atomic_fetch_add(z_p, partial,
                               __ATOMIC_RELAXED, __HIP_MEMORY_SCOPE_AGENT);
        __hip_atomic_fetch_add(cnt_p, 1u,
                               __ATOMIC_RELEASE, __HIP_MEMORY_SCOPE_AGENT);
    }

    // ---- batch-independent group-param fold (covers the wait) ----
    {
        const int t_ = tid >> 5, g_ = tid & 31;
        const int c_ = c0 + t_;
        float sg  = grp_w[g_ * C_ + c_] * rsqrtf(grp_rv[g_ * C_ + c_] + EPS_);
        float shv = grp_b[g_ * C_ + c_] - grp_rm[g_ * C_ + c_] * sg;
        #pragma unroll
        for (int off = 16; off; off >>= 1) {   // 32-wide halves: lanes 0,32 hold sums
            sg  += __shfl_down(sg, off);
            shv += __shfl_down(shv, off);
        }
        if (g_ == 0) {
            float msv  = sg  * (1.f / G_);
            float mshv = shv * (1.f / G_);
            float gsv  = g_w[c_] * rsqrtf(g_rv[c_] + EPS_);
            float gshv = g_b[c_] - g_rm[c_] * gsv;
            gs_sh[t_]  = gsv;
            gsh_sh[t_] = gshv;
            dsc_sh[t_] = msv  - gsv;
            dsh_sh[t_] = mshv - gshv;
        }
    }

    // ---- image-local barrier: relaxed poll, single acquire fence ----
    if (tid == 0) {
        while (__hip_atomic_load(cnt_p, __ATOMIC_RELAXED,
                                 __HIP_MEMORY_SCOPE_AGENT) < 32u) {
            __builtin_amdgcn_s_sleep(4);
        }
        __builtin_amdgcn_fence(__ATOMIC_ACQUIRE, "agent");
        float zv = __hip_atomic_load(z_p, __ATOMIC_RELAXED,
                                     __HIP_MEMORY_SCOPE_AGENT);
        a_sh = 1.f / (1.f + __expf(-(zv + alpha_b[0])));
    }
    __syncthreads();
    const float a = a_sh;

    // ---- phase 2: issue ALL chunk-2 + tail re-loads first (8-deep MLP), ----
    // ---- then stream stores: regs (chunks 0,1) + re-loaded (chunk 2, tail) ----
    v4f v2[PPB_], w[PPB_];
    #pragma unroll
    for (int t = 0; t < PPB_; ++t) {
        v2[t] = xb[t * HW4_ + 512 + tid];
        if (tid < 16) w[t] = xb[t * HW4_ + 768 + tid];
    }
    #pragma unroll
    for (int t = 0; t < PPB_; ++t) {
        const int base = t * HW4_;
        const float sc = fmaf(a, dsc_sh[t], gs_sh[t]);   // (1-a)*gs + a*ms
        const float sh = fmaf(a, dsh_sh[t], gsh_sh[t]);

        v4f r0, r1, r2;
        r0.x = fmaf(v0[t].x, sc, sh); r0.y = fmaf(v0[t].y, sc, sh);
        r0.z = fmaf(v0[t].z, sc, sh); r0.w = fmaf(v0[t].w, sc, sh);
        ob[base + tid] = r0;
        r1.x = fmaf(v1[t].x, sc, sh); r1.y = fmaf(v1[t].y, sc, sh);
        r1.z = fmaf(v1[t].z, sc, sh); r1.w = fmaf(v1[t].w, sc, sh);
        ob[base + 256 + tid] = r1;
        r2.x = fmaf(v2[t].x, sc, sh); r2.y = fmaf(v2[t].y, sc, sh);
        r2.z = fmaf(v2[t].z, sc, sh); r2.w = fmaf(v2[t].w, sc, sh);
        ob[base + 512 + tid] = r2;

        if (tid < 16) {
            v4f rw;
            rw.x = fmaf(w[t].x, sc, sh); rw.y = fmaf(w[t].y, sc, sh);
            rw.z = fmaf(w[t].z, sc, sh); rw.w = fmaf(w[t].w, sc, sh);
            ob[base + 768 + tid] = rw;
        }
    }
}

extern "C" void kernel_launch(void* const* d_in, const int* in_sizes, int n_in,
                              void* d_out, int out_size, void* d_ws, size_t ws_size,
                              hipStream_t stream) {
    const float* x       = (const float*)d_in[0];
    const float* alpha_w = (const float*)d_in[2];
    const float* alpha_b = (const float*)d_in[3];
    const float* g_w     = (const float*)d_in[4];
    const float* g_b     = (const float*)d_in[5];
    const float* g_rm    = (const float*)d_in[6];
    const float* g_rv    = (const float*)d_in[7];
    const float* grp_w   = (const float*)d_in[8];
    const float* grp_b   = (const float*)d_in[9];
    const float* grp_rm  = (const float*)d_in[10];
    const float* grp_rv  = (const float*)d_in[11];
    float* out = (float*)d_out;
    float* ws  = (float*)d_ws;

    // zero the 32 per-image {z, cnt} lines (ws is poisoned by the harness)
    hipMemsetAsync(ws, 0, B_ * 32 * sizeof(float), stream);

    fused_kernel<<<GRID_, 256, 0, stream>>>(x, alpha_w, alpha_b,
                                            g_w, g_b, g_rm, g_rv,
                                            grp_w, grp_b, grp_rm, grp_rv,
                                            ws, out);
}

// Round 7
// 209.154 us; speedup vs baseline: 1.0974x; 1.0974x over previous
//
#include <hip/hip_runtime.h>
#include <math.h>

#define B_ 32
#define C_ 256
#define HW_ 3136      // 56*56
#define HW4_ 784      // HW/4 (float4 chunks); 784 = 3*256 + 16
#define G_ 32
#define EPS_ 1e-5f

typedef float v4f __attribute__((ext_vector_type(4)));

// ws layout (floats):
//   [0 .. 8191]      zpart[b*C + c] = planesum(b,c) * alpha_w[c] / HW   (K1 -> K2)
//   [8192 .. 8447]   gs[c]
//   [8448 .. 8703]   gsh[c]
//   [8704 .. 8959]   dsc[c] = ms[c]  - gs[c]
//   [8960 .. 9215]   dsh[c] = msh[c] - gsh[c]
#define WS_Z    0
#define WS_GS   8192
#define WS_GSH  8448
#define WS_DSC  8704
#define WS_DSH  8960

// K1: one block per (b,c) plane. Pool the plane, fold alpha_w into the sum,
// single non-atomic store. Blocks bc<256 additionally fold the
// batch-independent affine params for channel c (one wave, all lanes active).
__global__ __launch_bounds__(256) void pool_kernel(
    const float* __restrict__ x, const float* __restrict__ alpha_w,
    const float* __restrict__ g_w, const float* __restrict__ g_b,
    const float* __restrict__ g_rm, const float* __restrict__ g_rv,
    const float* __restrict__ grp_w, const float* __restrict__ grp_b,
    const float* __restrict__ grp_rm, const float* __restrict__ grp_rv,
    float* __restrict__ ws)
{
    const int bc = blockIdx.x;
    const int c  = bc & (C_ - 1);
    const int tid = threadIdx.x;
    const int lane = tid & 63, wv = tid >> 6;
    const v4f* __restrict__ px = (const v4f*)(x + (size_t)bc * HW_);

    v4f a0 = px[tid];
    v4f a1 = px[tid + 256];
    v4f a2 = px[tid + 512];
    float s = a0.x + a0.y + a0.z + a0.w
            + a1.x + a1.y + a1.z + a1.w
            + a2.x + a2.y + a2.z + a2.w;
    if (tid < 16) {
        v4f a3 = px[tid + 768];
        s += a3.x + a3.y + a3.z + a3.w;
    }
    #pragma unroll
    for (int off = 32; off; off >>= 1) s += __shfl_down(s, off);
    __shared__ float red[4];
    if (lane == 0) red[wv] = s;
    __syncthreads();
    if (tid == 0)
        ws[WS_Z + bc] = (red[0] + red[1] + red[2] + red[3])
                        * (alpha_w[c] * (1.f / HW_));

    // batch-independent param fold: one wave, lanes 0..63 active (g = lane&31)
    if (bc < C_ && tid < 64) {
        const int g = tid & 31;
        float sg  = grp_w[g * C_ + c] * rsqrtf(grp_rv[g * C_ + c] + EPS_);
        float shv = grp_b[g * C_ + c] - grp_rm[g * C_ + c] * sg;
        #pragma unroll
        for (int off = 16; off; off >>= 1) {
            sg  += __shfl_down(sg, off);
            shv += __shfl_down(shv, off);
        }
        if (tid == 0) {   // lane0 = sum over groups 0..31
            float msv  = sg  * (1.f / G_);
            float mshv = shv * (1.f / G_);
            float gsv  = g_w[c] * rsqrtf(g_rv[c] + EPS_);
            float gshv = g_b[c] - g_rm[c] * gsv;
            ws[WS_GS  + c] = gsv;
            ws[WS_GSH + c] = gshv;
            ws[WS_DSC + c] = msv  - gsv;
            ws[WS_DSH + c] = mshv - gshv;
        }
    }
}

// K2: one block per (b,c) plane. x loads issued first; alpha = sigmoid of a
// single coalesced 256-float row-reduce (folded dot from K1); then
// load-fma-ntstore stream. No atomics, no fences, no occupancy cap.
__global__ __launch_bounds__(256) void apply_kernel(
    const float* __restrict__ x, const float* __restrict__ ws,
    const float* __restrict__ alpha_b, float* __restrict__ out)
{
    const int bc = blockIdx.x;
    const int c  = bc & (C_ - 1);
    const int b  = bc >> 8;
    const int tid = threadIdx.x;
    const int lane = tid & 63, wv = tid >> 6;
    const v4f* __restrict__ px = (const v4f*)(x + (size_t)bc * HW_);
    v4f* __restrict__ po = (v4f*)(out + (size_t)bc * HW_);

    // issue the bulk x loads before the prologue (latency overlap)
    v4f a0 = px[tid];
    v4f a1 = px[tid + 256];
    v4f a2 = px[tid + 512];
    v4f a3;
    if (tid < 16) a3 = px[tid + 768];

    // alpha[b]: reduce the pre-folded row zpart[b,:]
    float s = ws[WS_Z + b * C_ + tid];
    #pragma unroll
    for (int off = 32; off; off >>= 1) s += __shfl_down(s, off);
    __shared__ float red[4];
    __shared__ float a_sh;
    if (lane == 0) red[wv] = s;
    __syncthreads();
    if (tid == 0) {
        float z = red[0] + red[1] + red[2] + red[3] + alpha_b[0];
        a_sh = 1.f / (1.f + __expf(-z));
    }
    __syncthreads();
    const float a = a_sh;

    const float sc = fmaf(a, ws[WS_DSC + c], ws[WS_GS  + c]);  // (1-a)gs + a*ms
    const float sh = fmaf(a, ws[WS_DSH + c], ws[WS_GSH + c]);

    v4f r;
    r.x = fmaf(a0.x, sc, sh); r.y = fmaf(a0.y, sc, sh);
    r.z = fmaf(a0.z, sc, sh); r.w = fmaf(a0.w, sc, sh);
    __builtin_nontemporal_store(r, &po[tid]);
    r.x = fmaf(a1.x, sc, sh); r.y = fmaf(a1.y, sc, sh);
    r.z = fmaf(a1.z, sc, sh); r.w = fmaf(a1.w, sc, sh);
    __builtin_nontemporal_store(r, &po[tid + 256]);
    r.x = fmaf(a2.x, sc, sh); r.y = fmaf(a2.y, sc, sh);
    r.z = fmaf(a2.z, sc, sh); r.w = fmaf(a2.w, sc, sh);
    __builtin_nontemporal_store(r, &po[tid + 512]);
    if (tid < 16) {
        r.x = fmaf(a3.x, sc, sh); r.y = fmaf(a3.y, sc, sh);
        r.z = fmaf(a3.z, sc, sh); r.w = fmaf(a3.w, sc, sh);
        __builtin_nontemporal_store(r, &po[tid + 768]);
    }
}

extern "C" void kernel_launch(void* const* d_in, const int* in_sizes, int n_in,
                              void* d_out, int out_size, void* d_ws, size_t ws_size,
                              hipStream_t stream) {
    const float* x       = (const float*)d_in[0];
    const float* alpha_w = (const float*)d_in[2];
    const float* alpha_b = (const float*)d_in[3];
    const float* g_w     = (const float*)d_in[4];
    const float* g_b     = (const float*)d_in[5];
    const float* g_rm    = (const float*)d_in[6];
    const float* g_rv    = (const float*)d_in[7];
    const float* grp_w   = (const float*)d_in[8];
    const float* grp_b   = (const float*)d_in[9];
    const float* grp_rm  = (const float*)d_in[10];
    const float* grp_rv  = (const float*)d_in[11];
    float* out = (float*)d_out;
    float* ws  = (float*)d_ws;

    pool_kernel<<<B_ * C_, 256, 0, stream>>>(x, alpha_w,
                                             g_w, g_b, g_rm, g_rv,
                                             grp_w, grp_b, grp_rm, grp_rv, ws);
    apply_kernel<<<B_ * C_, 256, 0, stream>>>(x, ws, alpha_b, out);
}